// Round 6
// baseline (110.047 us; speedup 1.0000x reference)
//
#include <hip/hip_runtime.h>

// Quantized 3x3 conv, stride 1, pad 1 (MI355X / gfx950):
//   x: [32,64,112,112] fp32 -> uint4-range [0,15]
//   w: [128,64,3,3]    fp32 -> int4-range  [-8,7]
//   out: [32,128,112,112] fp32 (integer-exact)
//
// k_prep: blocks 0..287 quantize+reorder weights -> wq[cout][kh][kw][cin];
//         blocks 288+: quantize+transpose x -> xq[n][hp][wp][c] int8
//         (padded 114x114, zero border). LDS-bounce so global writes are
//         fully contiguous 1KB per wave instruction.
// k_conv: implicit GEMM, v_mfma_i32_16x16x64_i8.
//         Block = 512 thr / 8 waves, ALL 128 couts' weights in LDS (75.8 KB
//         -> exactly 2 blocks/CU = 32 waves/CU = 100% occupancy).
//         Wave = 64 sp x 64 co (4x4 tiles), ks+1 A-prefetch, XCD swizzle.

#define CIN  64
#define HH   112
#define WW   112
#define HW   (HH * WW)
#define COUT 128
#define KTOT 576              // 64*3*3
#define HP   114
#define WP   114
#define LDSW 592              // 576 + 16 pad

#define XQ_BYTES (32 * HP * WP * 64)     // 26,615,808
#define NWBLK 288                        // weight blocks (288*256 = 73728)
#define NXBLK (32 * 57)                  // activation blocks (2 rows each)
#define NCONV 1568                       // 32*49 = 8*196 (bijective XCD chunking)

typedef __attribute__((ext_vector_type(4))) int int32x4;

__global__ __launch_bounds__(256) void k_prep(const float* __restrict__ x,
                                              const float* __restrict__ w,
                                              char* __restrict__ xq,
                                              char* __restrict__ wq) {
    __shared__ char xsl[4 * 4096];        // [ch][tid] 16B units, 16 KB
    const int bid = blockIdx.x, tid = threadIdx.x;
    if (bid < NWBLK) {
        // ---- weights: wq[o][kh][kw][c] ----
        int idx = bid * 256 + tid;
        int o  = idx / KTOT;
        int r  = idx % KTOT;
        int kh = r / 192;
        int kw = (r / 64) % 3;
        int c  = r % 64;
        float q = fminf(fmaxf(rintf(w[((o * CIN + c) * 3 + kh) * 3 + kw]), -8.0f), 7.0f);
        wq[idx] = (char)(int)q;
        return;
    }
    // ---- activations: 2 padded rows per block ----
    const int rid = bid - NWBLK;          // 0..1823
    const int n   = rid / 57;
    const int hp0 = (rid % 57) * 2;
    const int hp  = hp0 + (tid >> 7);
    const int wp  = tid & 127;
    const bool inb = (hp >= 1) && (hp <= HH) && (wp >= 1) && (wp <= WW);
    const float* px = x + (((size_t)n * CIN) * HH + (hp - 1)) * WW + (wp - 1);
#pragma unroll
    for (int cw = 0; cw < 16; ++cw) {
        unsigned int word = 0;
        if (inb) {
#pragma unroll
            for (int j = 0; j < 4; ++j) {
                float v = px[(size_t)(cw * 4 + j) * HW];
                float q = fminf(fmaxf(rintf(v), 0.0f), 15.0f);
                word |= ((unsigned int)(int)q) << (8 * j);
            }
        }
        *(unsigned int*)(&xsl[(cw >> 2) * 4096 + tid * 16 + (cw & 3) * 4]) = word;
    }
    __syncthreads();
    // copy-out: 1024 16B units; lanes -> consecutive dest bytes (1KB/wave instr)
#pragma unroll
    for (int k = 0; k < 4; ++k) {
        const int u   = tid + k * 256;
        const int r   = u >> 9;
        const int rem = u & 511;
        const int dwp = rem >> 2;
        const int ch  = rem & 3;
        if (dwp < WP) {
            int32x4 v = *(const int32x4*)(&xsl[ch * 4096 + (r * 128 + dwp) * 16]);
            *(int32x4*)(xq + (((size_t)n * HP + hp0 + r) * WP + dwp) * 64 + ch * 16) = v;
        }
    }
}

__global__ __launch_bounds__(512) void k_conv(const char* __restrict__ xq,
                                              const char* __restrict__ wq,
                                              float* __restrict__ out) {
    __shared__ char wlds[COUT * LDSW];   // 75,776 B -> 2 blocks/CU

    const int tid = threadIdx.x;
    // XCD chunking (1568 = 8*196, bijective): consecutive nids = consecutive
    // spatial chunks of the same image -> halo-row L2 reuse within an XCD.
    const int nid   = (blockIdx.x & 7) * (NCONV / 8) + (blockIdx.x >> 3);
    const int n     = nid / 49;                  // 12544 = 49*256
    const int chunk = nid % 49;

    // ---- stage all 128 couts' weights: 4608 16B units / 512 thr = 9 each ----
    for (int i = tid; i < COUT * (KTOT / 16); i += 512) {
        int row = i / 36, ch = i % 36;
        *(int32x4*)(&wlds[row * LDSW + ch * 16]) =
            *(const int32x4*)(wq + row * KTOT + ch * 16);
    }
    __syncthreads();

    const int wave = tid >> 6;            // 0..7
    const int lane = tid & 63;
    const int l15  = lane & 15;
    const int lk   = lane >> 4;
    const int spg  = wave >> 1;           // 0..3: spatial sub-tile
    const int cobase = (wave & 1) * 64;   // cout half

    const int s0 = chunk * 256 + spg * 64;
    const char* xbase = xq + (size_t)n * (HP * WP * 64);

    int saddr[4];
#pragma unroll
    for (int tS = 0; tS < 4; ++tS) {
        int sl = s0 + tS * 16 + l15;
        int hh = sl / WW;
        int ww = sl - hh * WW;
        saddr[tS] = (hh * WP + ww) * 64 + lk * 16;
    }

    int32x4 acc[4][4];   // [tS][tO]
#pragma unroll
    for (int i = 0; i < 4; ++i)
#pragma unroll
        for (int j = 0; j < 4; ++j) acc[i][j] = (int32x4)(0);

    int32x4 af[4], afn[4];
#pragma unroll
    for (int tS = 0; tS < 4; ++tS)
        af[tS] = *(const int32x4*)(xbase + saddr[tS]);       // ks=0

#pragma unroll
    for (int ks = 0; ks < 9; ++ks) {
        if (ks < 8) {
            const int ksn = ks + 1;
            const int koffn = ((ksn / 3) * WP + (ksn % 3)) * 64;
#pragma unroll
            for (int tS = 0; tS < 4; ++tS)
                afn[tS] = *(const int32x4*)(xbase + saddr[tS] + koffn);
        }
#pragma unroll
        for (int tO = 0; tO < 4; ++tO) {
            const int32x4 bf = *(const int32x4*)(
                &wlds[(cobase + tO * 16 + l15) * LDSW + lk * 16 + ks * 64]);
#pragma unroll
            for (int tS = 0; tS < 4; ++tS)
                acc[tS][tO] = __builtin_amdgcn_mfma_i32_16x16x64_i8(af[tS], bf, acc[tS][tO], 0, 0, 0);
        }
#pragma unroll
        for (int tS = 0; tS < 4; ++tS) af[tS] = afn[tS];
    }

    // ---- epilogue: D col(l15)=cout, row(lk*4+reg)=spatial -> float4 stores ----
    float* obase = out + (size_t)n * (COUT * HW);
#pragma unroll
    for (int tS = 0; tS < 4; ++tS) {
#pragma unroll
        for (int tO = 0; tO < 4; ++tO) {
            const int co = cobase + tO * 16 + l15;
            const int sl = s0 + tS * 16 + lk * 4;
            float4 v;
            v.x = (float)acc[tS][tO][0];
            v.y = (float)acc[tS][tO][1];
            v.z = (float)acc[tS][tO][2];
            v.w = (float)acc[tS][tO][3];
            *(float4*)(&obase[(size_t)co * HW + sl]) = v;
        }
    }
}

extern "C" void kernel_launch(void* const* d_in, const int* in_sizes, int n_in,
                              void* d_out, int out_size, void* d_ws, size_t ws_size,
                              hipStream_t stream) {
    const float* x = (const float*)d_in[0];
    const float* w = (const float*)d_in[1];
    float* out = (float*)d_out;

    char* xq = (char*)d_ws;
    char* wq = xq + XQ_BYTES;

    hipLaunchKernelGGL(k_prep, dim3(NWBLK + NXBLK), dim3(256), 0, stream, x, w, xq, wq);
    hipLaunchKernelGGL(k_conv, dim3(NCONV), dim3(512), 0, stream, xq, wq, out);
}

// Round 7
// 105.365 us; speedup vs baseline: 1.0444x; 1.0444x over previous
//
#include <hip/hip_runtime.h>

// Quantized 3x3 conv, stride 1, pad 1 (MI355X / gfx950):
//   x: [32,64,112,112] fp32 -> uint4-range [0,15]
//   w: [128,64,3,3]    fp32 -> int4-range  [-8,7]
//   out: [32,128,112,112] fp32 (integer-exact)
//
// R5 skeleton (best measured 105.9 us) + ONE change: weights are stored in
// FRAGMENT-MAJOR order wq[half][ks][tO][lane][16B] so the conv's B-fragment
// LDS read is wlds[(ks*4+tO)*1024 + lane*16]: each lane reads its own 16 B,
// bank-conflict-free (lane*4 mod 32 = uniform 8 accesses/bank), fully
// sequential 1 KB per wave-read; LDS staging is a pure linear copy.
//
// k_prep: blocks 0..287 quantize weights -> fragment-major wq;
//         blocks 288+: quantize+transpose x -> xq[n][hp][wp][c] int8
//         (padded 114x114, zero border).
// k_conv: implicit GEMM, v_mfma_i32_16x16x64_i8. Block = 256 thr / 4 waves,
//         one 64-cout half's weights in LDS (36,864 B -> 4 blocks/CU).
//         2 sequential 256-sp chunks/block, ks+1 A-prefetch, XCD swizzle.

#define CIN  64
#define HH   112
#define WW   112
#define HW   (HH * WW)
#define COUT 128
#define KTOT 576              // 64*3*3
#define HP   114
#define WP   114
#define WHALF 36864           // 64 couts * 576 bytes, fragment-major

#define XQ_BYTES (32 * HP * WP * 64)     // 26,615,808
#define NWBLK 288                        // weight blocks (288*256 = 73728)
#define NXBLK (32 * 57)                  // activation blocks (2 rows each)
#define NCONV 1568                       // 8 * 196 (bijective XCD chunking)

typedef __attribute__((ext_vector_type(4))) int int32x4;

__global__ __launch_bounds__(256) void k_prep(const float* __restrict__ x,
                                              const float* __restrict__ w,
                                              char* __restrict__ xq,
                                              char* __restrict__ wq) {
    const int bid = blockIdx.x, tid = threadIdx.x;
    if (bid < NWBLK) {
        // ---- weights, fragment-major: idx = dest byte ----
        // idx = h*36864 + ks*4096 + tO*1024 + lane*16 + j
        // -> cout = h*64 + tO*16 + (lane&15), c = (lane>>4)*16 + j, kh=ks/3, kw=ks%3
        int idx = bid * 256 + tid;
        int h   = idx / WHALF;
        int r1  = idx % WHALF;
        int ks  = r1 / 4096;
        int r2  = r1 % 4096;
        int tO  = r2 / 1024;
        int r3  = r2 % 1024;
        int ln  = r3 / 16;
        int j   = r3 % 16;
        int o   = h * 64 + tO * 16 + (ln & 15);
        int c   = (ln >> 4) * 16 + j;
        int kh  = ks / 3, kw = ks % 3;
        float q = fminf(fmaxf(rintf(w[((o * CIN + c) * 3 + kh) * 3 + kw]), -8.0f), 7.0f);
        wq[idx] = (char)(int)q;
        return;
    }
    // ---- activations: xq[n][hp][wp][c], zero border ----
    const int rid = bid - NWBLK;          // 0..1823
    const int n  = rid / 57;
    const int hp = (rid % 57) * 2 + (tid >> 7);
    const int wp = tid & 127;
    if (wp >= WP) return;
    char* dst = xq + (((size_t)n * HP + hp) * WP + wp) * 64;
    int32x4* d4 = (int32x4*)dst;
    if (hp == 0 || hp == HP - 1 || wp == 0 || wp == WP - 1) {
#pragma unroll
        for (int i = 0; i < 4; ++i) d4[i] = (int32x4)(0);
        return;
    }
    const int h = hp - 1, ww = wp - 1;
    const float* px = x + (((size_t)n * CIN) * HH + h) * WW + ww;
    unsigned int buf[16];
#pragma unroll
    for (int cw = 0; cw < 16; ++cw) {
        unsigned int word = 0;
#pragma unroll
        for (int j = 0; j < 4; ++j) {
            float v = px[(size_t)(cw * 4 + j) * HW];
            float q = fminf(fmaxf(rintf(v), 0.0f), 15.0f);
            word |= ((unsigned int)(int)q) << (8 * j);
        }
        buf[cw] = word;
    }
#pragma unroll
    for (int i = 0; i < 4; ++i) {
        int32x4 v;
        v.x = (int)buf[i * 4 + 0];
        v.y = (int)buf[i * 4 + 1];
        v.z = (int)buf[i * 4 + 2];
        v.w = (int)buf[i * 4 + 3];
        d4[i] = v;
    }
}

__global__ __launch_bounds__(256) void k_conv(const char* __restrict__ xq,
                                              const char* __restrict__ wq,
                                              float* __restrict__ out) {
    __shared__ char wlds[WHALF];   // 36,864 B -> 4 blocks/CU

    const int tid = threadIdx.x;
    // XCD chunking (1568 = 8*196, bijective). Within a chunk, ids are
    // consecutive: nid 2k/2k+1 = the two cout-halves of spatial chunk-pair k.
    const int nid  = (blockIdx.x & 7) * (NCONV / 8) + (blockIdx.x >> 3);
    const int half = nid & 1;
    const int pb   = nid >> 1;          // 0..783, chunk pair {2pb, 2pb+1}

    // ---- stage this half's weights: linear copy, 2304 x 16B / 256 thr ----
    const char* wsrc = wq + (size_t)half * WHALF;
    for (int i = tid; i < WHALF / 16; i += 256)
        *(int32x4*)(&wlds[i * 16]) = *(const int32x4*)(wsrc + i * 16);
    __syncthreads();

    const int wave = tid >> 6;
    const int lane = tid & 63;
    const int l15  = lane & 15;
    const int lk   = lane >> 4;

#pragma unroll
    for (int it = 0; it < 2; ++it) {
        const int chunk = pb * 2 + it;           // 0..1567, 256 sp each
        const int n  = chunk / 49;               // 12544 = 49*256
        const int s0 = (chunk % 49) * 256 + wave * 64;
        const char* xbase = xq + (size_t)n * (HP * WP * 64);

        int saddr[4];
#pragma unroll
        for (int tS = 0; tS < 4; ++tS) {
            int sl = s0 + tS * 16 + l15;
            int hh = sl / WW;
            int ww = sl - hh * WW;
            saddr[tS] = (hh * WP + ww) * 64 + lk * 16;
        }

        int32x4 acc[4][4];   // [tS][tO]
#pragma unroll
        for (int i = 0; i < 4; ++i)
#pragma unroll
            for (int j = 0; j < 4; ++j) acc[i][j] = (int32x4)(0);

        int32x4 af[4], afn[4];
#pragma unroll
        for (int tS = 0; tS < 4; ++tS)
            af[tS] = *(const int32x4*)(xbase + saddr[tS]);   // ks=0: koff=0

#pragma unroll
        for (int ks = 0; ks < 9; ++ks) {
            if (ks < 8) {
                const int ksn = ks + 1;
                const int koffn = ((ksn / 3) * WP + (ksn % 3)) * 64;
#pragma unroll
                for (int tS = 0; tS < 4; ++tS)
                    afn[tS] = *(const int32x4*)(xbase + saddr[tS] + koffn);
            }
#pragma unroll
            for (int tO = 0; tO < 4; ++tO) {
                const int32x4 bf = *(const int32x4*)(
                    &wlds[(ks * 4 + tO) * 1024 + lane * 16]);
#pragma unroll
                for (int tS = 0; tS < 4; ++tS)
                    acc[tS][tO] = __builtin_amdgcn_mfma_i32_16x16x64_i8(af[tS], bf, acc[tS][tO], 0, 0, 0);
            }
#pragma unroll
            for (int tS = 0; tS < 4; ++tS) af[tS] = afn[tS];
        }

        // ---- epilogue: D col(l15)=cout, row(lk*4+reg)=spatial ----
        float* obase = out + (size_t)n * (COUT * HW) + (size_t)half * 64 * HW;
#pragma unroll
        for (int tS = 0; tS < 4; ++tS) {
#pragma unroll
            for (int tO = 0; tO < 4; ++tO) {
                const int co = tO * 16 + l15;
                const int sl = s0 + tS * 16 + lk * 4;
                float4 v;
                v.x = (float)acc[tS][tO][0];
                v.y = (float)acc[tS][tO][1];
                v.z = (float)acc[tS][tO][2];
                v.w = (float)acc[tS][tO][3];
                *(float4*)(&obase[(size_t)co * HW + sl]) = v;
            }
        }
    }
}

extern "C" void kernel_launch(void* const* d_in, const int* in_sizes, int n_in,
                              void* d_out, int out_size, void* d_ws, size_t ws_size,
                              hipStream_t stream) {
    const float* x = (const float*)d_in[0];
    const float* w = (const float*)d_in[1];
    float* out = (float*)d_out;

    char* xq = (char*)d_ws;
    char* wq = xq + XQ_BYTES;

    hipLaunchKernelGGL(k_prep, dim3(NWBLK + NXBLK), dim3(256), 0, stream, x, w, xq, wq);
    hipLaunchKernelGGL(k_conv, dim3(NCONV), dim3(256), 0, stream, xq, wq, out);
}

// Round 8
// 90.624 us; speedup vs baseline: 1.2143x; 1.1627x over previous
//
#include <hip/hip_runtime.h>

// Quantized 3x3 conv, stride 1, pad 1 (MI355X / gfx950):
//   x: [32,64,112,112] fp32 -> uint4-range [0,15]
//   w: [128,64,3,3]    fp32 -> int4-range  [-8,7]
//   out: [32,128,112,112] fp32 (integer-exact)
//
// R8: conv stages its activation strip in LDS so each xq byte is read from
// memory ONCE per block (was 9x gross -> L2/L3/HBM thrash; every prior conv
// variant pinned at ~80 us from that traffic).
//
// k_prep: blocks 0..287: quantize weights -> fragment-major
//           wq[ks][coTile(8)][lane(64)][16B]  (exact MFMA B-fragment order)
//         blocks 288+ : quantize+transpose x -> xq[n][hp][wp][c] int8
//           (padded 114x114, zero border)  -- unchanged, ~BW-floor.
// k_conv: block = 2 output rows x 128 cout, 512 thr / 8 waves.
//         Stage padded rows h0..h0+3 (29,184 contiguous bytes of xq) into
//         LDS with a linear coalesced copy. Wave = 1 row (7x16 sp) x 32 co.
//         Weights from global L2 (1KB contiguous per wave-read, ks+1
//         prefetch). 14 MFMA v_mfma_i32_16x16x64_i8 per ks per wave.

#define CIN  64
#define HH   112
#define WW   112
#define HW   (HH * WW)
#define COUT 128
#define HP   114
#define WP   114
#define KTOT 576

#define XQ_BYTES (32 * HP * WP * 64)     // 26,615,808
#define NWBLK 288                        // 288*256 = 73728 weight bytes
#define NXBLK (32 * 57)                  // activation prep blocks (2 rows each)
#define NCONV 1792                       // 32 img * 56 row-pairs = 8 * 224

#define SLAB_BYTES (4 * WP * 64)         // 29,184 B (4 padded rows)
#define SLAB_U16   (SLAB_BYTES / 16)     // 1824 16-byte units

typedef __attribute__((ext_vector_type(4))) int int32x4;

__global__ __launch_bounds__(256) void k_prep(const float* __restrict__ x,
                                              const float* __restrict__ w,
                                              char* __restrict__ xq,
                                              char* __restrict__ wq) {
    const int bid = blockIdx.x, tid = threadIdx.x;
    if (bid < NWBLK) {
        // ---- weights, fragment-major: idx = dest byte ----
        // idx = ks*8192 + ct*1024 + ln*16 + j
        // -> cout = ct*16 + (ln&15), c = (ln>>4)*16 + j, kh = ks/3, kw = ks%3
        int idx = bid * 256 + tid;
        int ks  = idx / 8192;
        int r2  = idx % 8192;
        int ct  = r2 / 1024;
        int r3  = r2 % 1024;
        int ln  = r3 / 16;
        int j   = r3 % 16;
        int o   = ct * 16 + (ln & 15);
        int c   = (ln >> 4) * 16 + j;
        int kh  = ks / 3, kw = ks % 3;
        float q = fminf(fmaxf(rintf(w[((o * CIN + c) * 3 + kh) * 3 + kw]), -8.0f), 7.0f);
        wq[idx] = (char)(int)q;
        return;
    }
    // ---- activations: xq[n][hp][wp][c], zero border ----
    const int rid = bid - NWBLK;          // 0..1823
    const int n  = rid / 57;
    const int hp = (rid % 57) * 2 + (tid >> 7);
    const int wp = tid & 127;
    if (wp >= WP) return;
    char* dst = xq + (((size_t)n * HP + hp) * WP + wp) * 64;
    int32x4* d4 = (int32x4*)dst;
    if (hp == 0 || hp == HP - 1 || wp == 0 || wp == WP - 1) {
#pragma unroll
        for (int i = 0; i < 4; ++i) d4[i] = (int32x4)(0);
        return;
    }
    const int h = hp - 1, ww = wp - 1;
    const float* px = x + (((size_t)n * CIN) * HH + h) * WW + ww;
    unsigned int buf[16];
#pragma unroll
    for (int cw = 0; cw < 16; ++cw) {
        unsigned int word = 0;
#pragma unroll
        for (int j = 0; j < 4; ++j) {
            float v = px[(size_t)(cw * 4 + j) * HW];
            float q = fminf(fmaxf(rintf(v), 0.0f), 15.0f);
            word |= ((unsigned int)(int)q) << (8 * j);
        }
        buf[cw] = word;
    }
#pragma unroll
    for (int i = 0; i < 4; ++i) {
        int32x4 v;
        v.x = (int)buf[i * 4 + 0];
        v.y = (int)buf[i * 4 + 1];
        v.z = (int)buf[i * 4 + 2];
        v.w = (int)buf[i * 4 + 3];
        d4[i] = v;
    }
}

__global__ __launch_bounds__(512, 4) void k_conv(const char* __restrict__ xq,
                                                 const char* __restrict__ wq,
                                                 float* __restrict__ out) {
    __shared__ char slab[SLAB_BYTES];     // 29,184 B: padded rows h0..h0+3

    const int tid = threadIdx.x;
    // XCD chunking (1792 = 8*224, bijective): consecutive nids = consecutive
    // row-pairs of the same image -> halo-row L2 reuse within an XCD.
    const int nid = (blockIdx.x & 7) * (NCONV / 8) + (blockIdx.x >> 3);
    const int n   = nid / 56;
    const int h0  = (nid % 56) * 2;

    // ---- stage: rows h0..h0+3 of xq are CONTIGUOUS -> linear memcpy ----
    const char* src = xq + (size_t)n * (HP * WP * 64) + (size_t)h0 * (WP * 64);
#pragma unroll
    for (int k = 0; k < 4; ++k) {
        const int u = tid + k * 512;
        if (u < SLAB_U16)
            *(int32x4*)(&slab[u * 16]) = *(const int32x4*)(src + u * 16);
    }
    __syncthreads();

    const int wave = tid >> 6;            // 0..7
    const int lane = tid & 63;
    const int l15  = lane & 15;
    const int lk   = lane >> 4;           // 16-byte k-chunk within 64 channels
    const int rw   = wave >> 2;           // output row within pair (0..1)
    const int Q    = wave & 3;            // cout quarter (32 couts)

    // B (weights, fragment-major): frag(ks, ct=Q*2+tO) at (ks*8+ct)*1024 + lane*16
    const char* wbase = wq + (Q * 2) * 1024 + lane * 16;

    int32x4 acc[7][2];
#pragma unroll
    for (int i = 0; i < 7; ++i) {
        acc[i][0] = (int32x4)(0);
        acc[i][1] = (int32x4)(0);
    }

    int32x4 bf[2], bfn[2];
    bf[0] = *(const int32x4*)(wbase);
    bf[1] = *(const int32x4*)(wbase + 1024);

#pragma unroll
    for (int ks = 0; ks < 9; ++ks) {
        if (ks < 8) {
            bfn[0] = *(const int32x4*)(wbase + (ks + 1) * 8192);
            bfn[1] = *(const int32x4*)(wbase + (ks + 1) * 8192 + 1024);
        }
        const int kh = ks / 3, kw = ks % 3;
        // A: slab row (rw+kh), padded col (wt*16 + l15 + kw), chunk lk
        const char* arow = &slab[(((rw + kh) * WP) + l15 + kw) * 64 + lk * 16];
        int32x4 af[7];
#pragma unroll
        for (int wt = 0; wt < 7; ++wt)
            af[wt] = *(const int32x4*)(arow + wt * 1024);   // wt*16 cols * 64B
#pragma unroll
        for (int tO = 0; tO < 2; ++tO)
#pragma unroll
            for (int wt = 0; wt < 7; ++wt)
                acc[wt][tO] = __builtin_amdgcn_mfma_i32_16x16x64_i8(af[wt], bf[tO], acc[wt][tO], 0, 0, 0);
        bf[0] = bfn[0];
        bf[1] = bfn[1];
    }

    // ---- epilogue: D col(l15)=cout, row(lk*4+reg)=spatial w -> float4 ----
    const int hgl = h0 + rw;
#pragma unroll
    for (int wt = 0; wt < 7; ++wt) {
#pragma unroll
        for (int tO = 0; tO < 2; ++tO) {
            const int co = Q * 32 + tO * 16 + l15;
            float4 v;
            v.x = (float)acc[wt][tO][0];
            v.y = (float)acc[wt][tO][1];
            v.z = (float)acc[wt][tO][2];
            v.w = (float)acc[wt][tO][3];
            *(float4*)(&out[(((size_t)n * COUT + co) * HH + hgl) * WW + wt * 16 + lk * 4]) = v;
        }
    }
}

extern "C" void kernel_launch(void* const* d_in, const int* in_sizes, int n_in,
                              void* d_out, int out_size, void* d_ws, size_t ws_size,
                              hipStream_t stream) {
    const float* x = (const float*)d_in[0];
    const float* w = (const float*)d_in[1];
    float* out = (float*)d_out;

    char* xq = (char*)d_ws;
    char* wq = xq + XQ_BYTES;

    hipLaunchKernelGGL(k_prep, dim3(NWBLK + NXBLK), dim3(256), 0, stream, x, w, xq, wq);
    hipLaunchKernelGGL(k_conv, dim3(NCONV), dim3(512), 0, stream, xq, wq, out);
}

// Round 9
// 87.194 us; speedup vs baseline: 1.2621x; 1.0393x over previous
//
#include <hip/hip_runtime.h>

// Quantized 3x3 conv, stride 1, pad 1 (MI355X / gfx950):
//   x: [32,64,112,112] fp32 -> uint4-range [0,15]
//   w: [128,64,3,3]    fp32 -> int4-range  [-8,7]
//   out: [32,128,112,112] fp32 (integer-exact)
//
// R9 = R8 (best, 90.6 us) + ONE change: weight B-fragment prefetch depth 2
// (covers ~200-450 cyc L2 latency; depth 1 only covered ~150 cyc -> every
// wave stalled on vmcnt each ks).
//
// k_prep: blocks 0..287: quantize weights -> fragment-major
//           wq[ks][coTile(8)][lane(64)][16B]  (exact MFMA B-fragment order)
//         blocks 288+ : quantize+transpose x -> xq[n][hp][wp][c] int8
//           (padded 114x114, zero border).
// k_conv: block = 2 output rows x 128 cout, 512 thr / 8 waves.
//         Stage padded rows h0..h0+3 (29,184 contiguous bytes of xq) into
//         LDS with a linear coalesced copy. Wave = 1 row (7x16 sp) x 32 co.
//         Weights from global L2, prefetch depth 2. 14 MFMA
//         v_mfma_i32_16x16x64_i8 per ks per wave.

#define CIN  64
#define HH   112
#define WW   112
#define HW   (HH * WW)
#define COUT 128
#define HP   114
#define WP   114
#define KTOT 576

#define XQ_BYTES (32 * HP * WP * 64)     // 26,615,808
#define NWBLK 288                        // 288*256 = 73728 weight bytes
#define NXBLK (32 * 57)                  // activation prep blocks (2 rows each)
#define NCONV 1792                       // 32 img * 56 row-pairs = 8 * 224

#define SLAB_BYTES (4 * WP * 64)         // 29,184 B (4 padded rows)
#define SLAB_U16   (SLAB_BYTES / 16)     // 1824 16-byte units

typedef __attribute__((ext_vector_type(4))) int int32x4;

__global__ __launch_bounds__(256) void k_prep(const float* __restrict__ x,
                                              const float* __restrict__ w,
                                              char* __restrict__ xq,
                                              char* __restrict__ wq) {
    const int bid = blockIdx.x, tid = threadIdx.x;
    if (bid < NWBLK) {
        // ---- weights, fragment-major: idx = dest byte ----
        // idx = ks*8192 + ct*1024 + ln*16 + j
        // -> cout = ct*16 + (ln&15), c = (ln>>4)*16 + j, kh = ks/3, kw = ks%3
        int idx = bid * 256 + tid;
        int ks  = idx / 8192;
        int r2  = idx % 8192;
        int ct  = r2 / 1024;
        int r3  = r2 % 1024;
        int ln  = r3 / 16;
        int j   = r3 % 16;
        int o   = ct * 16 + (ln & 15);
        int c   = (ln >> 4) * 16 + j;
        int kh  = ks / 3, kw = ks % 3;
        float q = fminf(fmaxf(rintf(w[((o * CIN + c) * 3 + kh) * 3 + kw]), -8.0f), 7.0f);
        wq[idx] = (char)(int)q;
        return;
    }
    // ---- activations: xq[n][hp][wp][c], zero border ----
    const int rid = bid - NWBLK;          // 0..1823
    const int n  = rid / 57;
    const int hp = (rid % 57) * 2 + (tid >> 7);
    const int wp = tid & 127;
    if (wp >= WP) return;
    char* dst = xq + (((size_t)n * HP + hp) * WP + wp) * 64;
    int32x4* d4 = (int32x4*)dst;
    if (hp == 0 || hp == HP - 1 || wp == 0 || wp == WP - 1) {
#pragma unroll
        for (int i = 0; i < 4; ++i) d4[i] = (int32x4)(0);
        return;
    }
    const int h = hp - 1, ww = wp - 1;
    const float* px = x + (((size_t)n * CIN) * HH + h) * WW + ww;
    unsigned int buf[16];
#pragma unroll
    for (int cw = 0; cw < 16; ++cw) {
        unsigned int word = 0;
#pragma unroll
        for (int j = 0; j < 4; ++j) {
            float v = px[(size_t)(cw * 4 + j) * HW];
            float q = fminf(fmaxf(rintf(v), 0.0f), 15.0f);
            word |= ((unsigned int)(int)q) << (8 * j);
        }
        buf[cw] = word;
    }
#pragma unroll
    for (int i = 0; i < 4; ++i) {
        int32x4 v;
        v.x = (int)buf[i * 4 + 0];
        v.y = (int)buf[i * 4 + 1];
        v.z = (int)buf[i * 4 + 2];
        v.w = (int)buf[i * 4 + 3];
        d4[i] = v;
    }
}

__global__ __launch_bounds__(512, 4) void k_conv(const char* __restrict__ xq,
                                                 const char* __restrict__ wq,
                                                 float* __restrict__ out) {
    __shared__ char slab[SLAB_BYTES];     // 29,184 B: padded rows h0..h0+3

    const int tid = threadIdx.x;
    // XCD chunking (1792 = 8*224, bijective): consecutive nids = consecutive
    // row-pairs of the same image -> halo-row L2 reuse within an XCD.
    const int nid = (blockIdx.x & 7) * (NCONV / 8) + (blockIdx.x >> 3);
    const int n   = nid / 56;
    const int h0  = (nid % 56) * 2;

    // ---- stage: rows h0..h0+3 of xq are CONTIGUOUS -> linear memcpy ----
    const char* src = xq + (size_t)n * (HP * WP * 64) + (size_t)h0 * (WP * 64);
#pragma unroll
    for (int k = 0; k < 4; ++k) {
        const int u = tid + k * 512;
        if (u < SLAB_U16)
            *(int32x4*)(&slab[u * 16]) = *(const int32x4*)(src + u * 16);
    }
    __syncthreads();

    const int wave = tid >> 6;            // 0..7
    const int lane = tid & 63;
    const int l15  = lane & 15;
    const int lk   = lane >> 4;           // 16-byte k-chunk within 64 channels
    const int rw   = wave >> 2;           // output row within pair (0..1)
    const int Q    = wave & 3;            // cout quarter (32 couts)

    // B (weights, fragment-major): frag(ks, ct=Q*2+tO) at (ks*8+ct)*1024 + lane*16
    const char* wbase = wq + (Q * 2) * 1024 + lane * 16;

    int32x4 acc[7][2];
#pragma unroll
    for (int i = 0; i < 7; ++i) {
        acc[i][0] = (int32x4)(0);
        acc[i][1] = (int32x4)(0);
    }

    // Weight prefetch depth 2: b0 = frag(ks), b1 = frag(ks+1), issue ks+2.
    int32x4 b0[2], b1[2], b2[2];
    b0[0] = *(const int32x4*)(wbase);
    b0[1] = *(const int32x4*)(wbase + 1024);
    b1[0] = *(const int32x4*)(wbase + 8192);
    b1[1] = *(const int32x4*)(wbase + 8192 + 1024);

#pragma unroll
    for (int ks = 0; ks < 9; ++ks) {
        {
            const int ksn = (ks + 2 <= 8) ? ks + 2 : 8;   // clamp: stay in-bounds
            b2[0] = *(const int32x4*)(wbase + ksn * 8192);
            b2[1] = *(const int32x4*)(wbase + ksn * 8192 + 1024);
        }
        const int kh = ks / 3, kw = ks % 3;
        // A: slab row (rw+kh), padded col (wt*16 + l15 + kw), chunk lk
        const char* arow = &slab[(((rw + kh) * WP) + l15 + kw) * 64 + lk * 16];
        int32x4 af[7];
#pragma unroll
        for (int wt = 0; wt < 7; ++wt)
            af[wt] = *(const int32x4*)(arow + wt * 1024);   // wt*16 cols * 64B
#pragma unroll
        for (int tO = 0; tO < 2; ++tO)
#pragma unroll
            for (int wt = 0; wt < 7; ++wt)
                acc[wt][tO] = __builtin_amdgcn_mfma_i32_16x16x64_i8(af[wt], b0[tO], acc[wt][tO], 0, 0, 0);
        b0[0] = b1[0]; b0[1] = b1[1];
        b1[0] = b2[0]; b1[1] = b2[1];
    }

    // ---- epilogue: D col(l15)=cout, row(lk*4+reg)=spatial w -> float4 ----
    const int hgl = h0 + rw;
#pragma unroll
    for (int wt = 0; wt < 7; ++wt) {
#pragma unroll
        for (int tO = 0; tO < 2; ++tO) {
            const int co = Q * 32 + tO * 16 + l15;
            float4 v;
            v.x = (float)acc[wt][tO][0];
            v.y = (float)acc[wt][tO][1];
            v.z = (float)acc[wt][tO][2];
            v.w = (float)acc[wt][tO][3];
            *(float4*)(&out[(((size_t)n * COUT + co) * HH + hgl) * WW + wt * 16 + lk * 4]) = v;
        }
    }
}

extern "C" void kernel_launch(void* const* d_in, const int* in_sizes, int n_in,
                              void* d_out, int out_size, void* d_ws, size_t ws_size,
                              hipStream_t stream) {
    const float* x = (const float*)d_in[0];
    const float* w = (const float*)d_in[1];
    float* out = (float*)d_out;

    char* xq = (char*)d_ws;
    char* wq = xq + XQ_BYTES;

    hipLaunchKernelGGL(k_prep, dim3(NWBLK + NXBLK), dim3(256), 0, stream, x, w, xq, wq);
    hipLaunchKernelGGL(k_conv, dim3(NCONV), dim3(512), 0, stream, xq, wq, out);
}